// Round 1
// baseline (142.223 us; speedup 1.0000x reference)
//
#include <hip/hip_runtime.h>
#include <math.h>

#define NN 50000
#define NE 800000
#define NH 4
#define HD 32
#define FD 128      // NH*HD == IN_DIM
#define NTILE 3125  // 50000 / 16 exactly
#define GEMM_BLOCKS 391                 // ceil(NTILE / 8 waves)
#define ROWS_BLOCKS ((NE + 511) / 512)  // 1563

typedef __attribute__((ext_vector_type(8))) short short8;
typedef __attribute__((ext_vector_type(4))) float floatx4;

__device__ __forceinline__ unsigned short f2bf(float f) {
    union { float f; unsigned u; } v; v.f = f;
    unsigned u = v.u;
    return (unsigned short)((u + 0x7FFFu + ((u >> 16) & 1u)) >> 16);
}
__device__ __forceinline__ float bf_lo(unsigned u) {
    union { unsigned u; float f; } v; v.u = u << 16; return v.f;
}
__device__ __forceinline__ float bf_hi(unsigned u) {
    union { unsigned u; float f; } v; v.u = u & 0xFFFF0000u; return v.f;
}

// ---------------------------------------------------------------------------
// Kernel 1: projection via bf16 MFMA with fused node-attention epilogue,
// PLUS the CSR row-offset builder fused as trailing blocks (independent of
// the GEMM, so it overlaps instead of costing a serialized dispatch).
// One 16-node tile per wave (391 blocks x 8 waves covers 3125 tiles).
// ---------------------------------------------------------------------------
__global__ __launch_bounds__(512) void k_gemm_rows(const float* __restrict__ x,
                                                   const float* __restrict__ W,
                                                   const float* __restrict__ al,
                                                   const float* __restrict__ ar,
                                                   const int* __restrict__ dst,
                                                   unsigned short* __restrict__ feat_bf,
                                                   float* __restrict__ el,
                                                   float* __restrict__ er,
                                                   int* __restrict__ rows) {
    const int tid = threadIdx.x;

    if (blockIdx.x >= GEMM_BLOCKS) {
        // ---- CSR row offsets from sorted dst ----
        int e = (blockIdx.x - GEMM_BLOCKS) * 512 + tid;
        if (e < NE) {
            int dj = dst[e];
            if (e == 0) {
                for (int n = 0; n <= dj; ++n) rows[n] = 0;
            } else {
                int prev = dst[e - 1];
                for (int n = prev + 1; n <= dj; ++n) rows[n] = e;
            }
            if (e == NE - 1) {
                for (int n = dj + 1; n <= NN; ++n) rows[n] = NE;
            }
        }
        return;
    }

    __shared__ unsigned short Wl[FD * 136];   // Wl[c][k], row stride 136 bf16
    for (int p = tid; p < FD * 64; p += 512) {
        int c = p >> 6, k2 = (p & 63) * 2;
        float2 wv = *(const float2*)&W[c * FD + k2];
        *(unsigned*)&Wl[c * 136 + k2] =
            (unsigned)f2bf(wv.x) | ((unsigned)f2bf(wv.y) << 16);
    }
    __syncthreads();

    const int wv_id = tid >> 6, lane = tid & 63;
    const int tile = blockIdx.x * 8 + wv_id;
    if (tile >= NTILE) return;                // after the only barrier: safe
    const int col = lane & 15, quad = lane >> 4;

    // attention vectors for this lane's 8 output cols (col + 16*ct)
    float alr[8], arr[8];
    #pragma unroll
    for (int ct = 0; ct < 8; ++ct) {
        alr[ct] = al[col + 16 * ct];
        arr[ct] = ar[col + 16 * ct];
    }

    const int n0 = tile * 16;

    short8 afrag[4];
    const float* xrow = x + (size_t)(n0 + col) * FD;
    #pragma unroll
    for (int s = 0; s < 4; ++s) {
        float4 u0 = *(const float4*)&xrow[s * 32 + quad * 8];
        float4 u1 = *(const float4*)&xrow[s * 32 + quad * 8 + 4];
        short8 a;
        a[0] = (short)f2bf(u0.x); a[1] = (short)f2bf(u0.y);
        a[2] = (short)f2bf(u0.z); a[3] = (short)f2bf(u0.w);
        a[4] = (short)f2bf(u1.x); a[5] = (short)f2bf(u1.y);
        a[6] = (short)f2bf(u1.z); a[7] = (short)f2bf(u1.w);
        afrag[s] = a;
    }

    floatx4 acc[8];
    #pragma unroll
    for (int ct = 0; ct < 8; ++ct) acc[ct] = (floatx4){0.f, 0.f, 0.f, 0.f};

    #pragma unroll
    for (int ct = 0; ct < 8; ++ct) {
        #pragma unroll
        for (int s = 0; s < 4; ++s) {
            short8 b = *(const short8*)&Wl[(ct * 16 + col) * 136 + s * 32 + quad * 8];
            acc[ct] = __builtin_amdgcn_mfma_f32_16x16x32_bf16(afrag[s], b, acc[ct], 0, 0, 0);
        }
    }

    // feat store (C/D: col = lane&15, row = quad*4 + reg)
    #pragma unroll
    for (int ct = 0; ct < 8; ++ct) {
        #pragma unroll
        for (int r = 0; r < 4; ++r) {
            feat_bf[(size_t)(n0 + quad * 4 + r) * FD + ct * 16 + col] = f2bf(acc[ct][r]);
        }
    }

    // fused el/er: head h owns cols 32h..32h+31 = lane cols ct in {2h, 2h+1}
    #pragma unroll
    for (int r = 0; r < 4; ++r) {
        float ev[8];
        #pragma unroll
        for (int hh = 0; hh < NH; ++hh) {
            ev[hh]     = acc[2 * hh][r] * alr[2 * hh] + acc[2 * hh + 1][r] * alr[2 * hh + 1];
            ev[4 + hh] = acc[2 * hh][r] * arr[2 * hh] + acc[2 * hh + 1][r] * arr[2 * hh + 1];
        }
        #pragma unroll
        for (int m = 1; m < 16; m <<= 1) {
            #pragma unroll
            for (int j = 0; j < 8; ++j) ev[j] += __shfl_xor(ev[j], m);
        }
        if (col == 0) {
            int n = n0 + quad * 4 + r;
            *(float4*)&el[n * NH] = make_float4(ev[0], ev[1], ev[2], ev[3]);
            *(float4*)&er[n * NH] = make_float4(ev[4], ev[5], ev[6], ev[7]);
        }
    }
}

// ---------------------------------------------------------------------------
// Kernel 2: aggregation with FUSED edge softmax. One wave per node.
// lane = 16*edge_slot + dim_slot (8 dims/lane). Lane's 4 edges are
// CONTIGUOUS (base = e + 4*q + u), so src is one aligned int4 load
// (loop base s & ~3 keeps 16B alignment). w = exp(leaky(el[src]+er[n]))
// computed in-register: no wE tensor, no second pass over edges.
// Tail lanes are exec-masked (no duplicate clamp gathers).
// Logits tiny (sigma~0.23) -> unshifted exp is exact-safe.
// ---------------------------------------------------------------------------
__global__ __launch_bounds__(256) void k_aggregate(const unsigned short* __restrict__ feat_bf,
                                                   const float* __restrict__ el,
                                                   const float* __restrict__ er,
                                                   const int* __restrict__ src,
                                                   const int* __restrict__ rows,
                                                   float* __restrict__ out) {
    const int wave = threadIdx.x >> 6;
    const int lane = threadIdx.x & 63;
    const int n = blockIdx.x * 4 + wave;
    if (n >= NN) return;

    const int s = __builtin_amdgcn_readfirstlane(rows[n]);
    const int t = __builtin_amdgcn_readfirstlane(rows[n + 1]);
    const int q  = lane >> 4;        // edge slot 0..3
    const int lp = lane & 15;        // dim slot: dims 8*lp .. 8*lp+7
    const int h  = lp >> 2;          // head of those dims
    const int dimoff = 8 * lp;

    const float erh = er[n * NH + h];

    float acc[8] = {0.f, 0.f, 0.f, 0.f, 0.f, 0.f, 0.f, 0.f};
    float den = 0.f;

    for (int e = (s & ~3); e < t; e += 16) {
        const int base = e + 4 * q;          // 4B-aligned index -> 16B src addr
        int sj4[4];
        const bool full4 = (base >= s) && (base + 3 < t);
        if (full4) {
            int4 sv = *(const int4*)&src[base];
            sj4[0] = sv.x; sj4[1] = sv.y; sj4[2] = sv.z; sj4[3] = sv.w;
        } else {
            #pragma unroll
            for (int u = 0; u < 4; ++u) {
                int ei = base + u;
                sj4[u] = (ei >= s && ei < t) ? src[ei] : 0;
            }
        }

        float elv[4];
        #pragma unroll
        for (int u = 0; u < 4; ++u) {
            int ei = base + u;
            if (ei >= s && ei < t) elv[u] = el[sj4[u] * NH + h];
        }
        uint4 uvv[4];
        #pragma unroll
        for (int u = 0; u < 4; ++u) {
            int ei = base + u;
            if (ei >= s && ei < t)
                uvv[u] = *(const uint4*)&feat_bf[(size_t)sj4[u] * FD + dimoff];
        }

        #pragma unroll
        for (int u = 0; u < 4; ++u) {
            int ei = base + u;
            if (ei >= s && ei < t) {
                float lg = elv[u] + erh;
                float w = __expf(fmaxf(lg, 0.2f * lg));
                uint4 uv = uvv[u];
                acc[0] += w * bf_lo(uv.x); acc[1] += w * bf_hi(uv.x);
                acc[2] += w * bf_lo(uv.y); acc[3] += w * bf_hi(uv.y);
                acc[4] += w * bf_lo(uv.z); acc[5] += w * bf_hi(uv.z);
                acc[6] += w * bf_lo(uv.w); acc[7] += w * bf_hi(uv.w);
                den += w;
            }
        }
    }

    // combine the 4 edge-groups (lanes differing in bits 4,5)
    #pragma unroll
    for (int m = 16; m < 64; m <<= 1) {
        #pragma unroll
        for (int j = 0; j < 8; ++j) acc[j] += __shfl_xor(acc[j], m);
        den += __shfl_xor(den, m);
    }

    if (q == 0) {
        const float rden = (den > 0.f) ? 1.f / den : 0.f;
        float* op = out + (size_t)n * FD + dimoff;
        *(float4*)op       = make_float4(acc[0] * rden, acc[1] * rden, acc[2] * rden, acc[3] * rden);
        *(float4*)(op + 4) = make_float4(acc[4] * rden, acc[5] * rden, acc[6] * rden, acc[7] * rden);
    }
}

// ---------------------------------------------------------------------------
extern "C" void kernel_launch(void* const* d_in, const int* in_sizes, int n_in,
                              void* d_out, int out_size, void* d_ws, size_t ws_size,
                              hipStream_t stream) {
    const float* x  = (const float*)d_in[0];
    const float* W  = (const float*)d_in[1];
    const float* al = (const float*)d_in[2];
    const float* ar = (const float*)d_in[3];
    const int* src  = (const int*)d_in[4];
    const int* dst  = (const int*)d_in[5];
    float* out = (float*)d_out;

    // ws: feat_bf[NN*FD] ushort | el[NN*NH] f32 | er[NN*NH] f32 | rows[NN+1]
    unsigned short* feat_bf = (unsigned short*)d_ws;
    float* el = (float*)(feat_bf + (size_t)NN * FD);
    float* er = el + (size_t)NN * NH;
    int*   rows = (int*)(er + (size_t)NN * NH);

    k_gemm_rows<<<GEMM_BLOCKS + ROWS_BLOCKS, 512, 0, stream>>>(x, W, al, ar, dst,
                                                               feat_bf, el, er, rows);
    k_aggregate<<<(NN + 3) / 4, 256, 0, stream>>>(feat_bf, el, er, src, rows, out);
}

// Round 2
// 136.296 us; speedup vs baseline: 1.0435x; 1.0435x over previous
//
#include <hip/hip_runtime.h>
#include <math.h>

#define NN 50000
#define NE 800000
#define NH 4
#define HD 32
#define FD 128      // NH*HD == IN_DIM
#define NTILE 3125  // 50000 / 16 exactly
#define GEMM_BLOCKS 256                 // grid-stride, 8 waves/block
#define ROWS_BLOCKS ((NE + 511) / 512)  // 1563
#define CAP 1024    // edges per LDS weight chunk (16 KB); typical block degree ~64

typedef __attribute__((ext_vector_type(8))) short short8;
typedef __attribute__((ext_vector_type(4))) float floatx4;

__device__ __forceinline__ unsigned short f2bf(float f) {
    union { float f; unsigned u; } v; v.f = f;
    unsigned u = v.u;
    return (unsigned short)((u + 0x7FFFu + ((u >> 16) & 1u)) >> 16);
}
__device__ __forceinline__ float bf_lo(unsigned u) {
    union { unsigned u; float f; } v; v.u = u << 16; return v.f;
}
__device__ __forceinline__ float bf_hi(unsigned u) {
    union { unsigned u; float f; } v; v.u = u & 0xFFFF0000u; return v.f;
}

// ---------------------------------------------------------------------------
// Kernel 1: projection via bf16 MFMA with fused node-attention epilogue
// (grid-stride over 16-node tiles, W staged to LDS ONCE per block),
// PLUS the CSR row-offset builder fused as trailing blocks (independent
// work -> overlaps the GEMM instead of costing a serialized dispatch).
// ---------------------------------------------------------------------------
__global__ __launch_bounds__(512) void k_gemm_rows(const float* __restrict__ x,
                                                   const float* __restrict__ W,
                                                   const float* __restrict__ al,
                                                   const float* __restrict__ ar,
                                                   const int* __restrict__ dst,
                                                   unsigned short* __restrict__ feat_bf,
                                                   float* __restrict__ el,
                                                   float* __restrict__ er,
                                                   int* __restrict__ rows) {
    const int tid = threadIdx.x;

    if (blockIdx.x >= GEMM_BLOCKS) {
        // ---- CSR row offsets from sorted dst ----
        int e = (blockIdx.x - GEMM_BLOCKS) * 512 + tid;
        if (e < NE) {
            int dj = dst[e];
            if (e == 0) {
                for (int n = 0; n <= dj; ++n) rows[n] = 0;
            } else {
                int prev = dst[e - 1];
                for (int n = prev + 1; n <= dj; ++n) rows[n] = e;
            }
            if (e == NE - 1) {
                for (int n = dj + 1; n <= NN; ++n) rows[n] = NE;
            }
        }
        return;
    }

    __shared__ unsigned short Wl[FD * 136];   // Wl[c][k], row stride 136 bf16
    for (int p = tid; p < FD * 64; p += 512) {
        int c = p >> 6, k2 = (p & 63) * 2;
        float2 wv = *(const float2*)&W[c * FD + k2];
        *(unsigned*)&Wl[c * 136 + k2] =
            (unsigned)f2bf(wv.x) | ((unsigned)f2bf(wv.y) << 16);
    }
    __syncthreads();

    const int wv_id = tid >> 6, lane = tid & 63;
    const int col = lane & 15, quad = lane >> 4;

    // attention vectors for this lane's 8 output cols (col + 16*ct)
    float alr[8], arr[8];
    #pragma unroll
    for (int ct = 0; ct < 8; ++ct) {
        alr[ct] = al[col + 16 * ct];
        arr[ct] = ar[col + 16 * ct];
    }

    for (int tile = blockIdx.x * 8 + wv_id; tile < NTILE; tile += GEMM_BLOCKS * 8) {
        const int n0 = tile * 16;

        short8 afrag[4];
        const float* xrow = x + (size_t)(n0 + col) * FD;
        #pragma unroll
        for (int s = 0; s < 4; ++s) {
            float4 u0 = *(const float4*)&xrow[s * 32 + quad * 8];
            float4 u1 = *(const float4*)&xrow[s * 32 + quad * 8 + 4];
            short8 a;
            a[0] = (short)f2bf(u0.x); a[1] = (short)f2bf(u0.y);
            a[2] = (short)f2bf(u0.z); a[3] = (short)f2bf(u0.w);
            a[4] = (short)f2bf(u1.x); a[5] = (short)f2bf(u1.y);
            a[6] = (short)f2bf(u1.z); a[7] = (short)f2bf(u1.w);
            afrag[s] = a;
        }

        floatx4 acc[8];
        #pragma unroll
        for (int ct = 0; ct < 8; ++ct) acc[ct] = (floatx4){0.f, 0.f, 0.f, 0.f};

        #pragma unroll
        for (int ct = 0; ct < 8; ++ct) {
            #pragma unroll
            for (int s = 0; s < 4; ++s) {
                short8 b = *(const short8*)&Wl[(ct * 16 + col) * 136 + s * 32 + quad * 8];
                acc[ct] = __builtin_amdgcn_mfma_f32_16x16x32_bf16(afrag[s], b, acc[ct], 0, 0, 0);
            }
        }

        // feat store (C/D: col = lane&15, row = quad*4 + reg)
        #pragma unroll
        for (int ct = 0; ct < 8; ++ct) {
            #pragma unroll
            for (int r = 0; r < 4; ++r) {
                feat_bf[(size_t)(n0 + quad * 4 + r) * FD + ct * 16 + col] = f2bf(acc[ct][r]);
            }
        }

        // fused el/er: head h owns cols 32h..32h+31 = lane cols ct in {2h, 2h+1}
        #pragma unroll
        for (int r = 0; r < 4; ++r) {
            float ev[8];
            #pragma unroll
            for (int hh = 0; hh < NH; ++hh) {
                ev[hh]     = acc[2 * hh][r] * alr[2 * hh] + acc[2 * hh + 1][r] * alr[2 * hh + 1];
                ev[4 + hh] = acc[2 * hh][r] * arr[2 * hh] + acc[2 * hh + 1][r] * arr[2 * hh + 1];
            }
            #pragma unroll
            for (int m = 1; m < 16; m <<= 1) {
                #pragma unroll
                for (int j = 0; j < 8; ++j) ev[j] += __shfl_xor(ev[j], m);
            }
            if (col == 0) {
                int n = n0 + quad * 4 + r;
                *(float4*)&el[n * NH] = make_float4(ev[0], ev[1], ev[2], ev[3]);
                *(float4*)&er[n * NH] = make_float4(ev[4], ev[5], ev[6], ev[7]);
            }
        }
    }
}

// ---------------------------------------------------------------------------
// Kernel 2: aggregation with BLOCK-LOCAL LDS softmax weights.
// Block = 4 consecutive nodes = one contiguous CSR edge range [s0, t3).
// Phase 1: 256 threads compute w[e][h]=exp(leaky(el[src]+er[dst])) ONCE per
//   edge (coalesced src/dst streams, float4 el/er) into a 16 KB LDS tile.
// Phase 2: per-wave gather loop (lane = 16*edge_slot + dim_slot, int4 src,
//   exec-masked tails); w is a cheap LDS read independent of the src gather
//   -> no dependent el gather, no redundant exp in the hot loop.
// Chunked at CAP edges with a barrier loop: unconditionally correct for any
// degree distribution (typical block degree ~64 -> single chunk).
// Logits tiny (sigma~0.23) -> unshifted exp is exact-safe.
// ---------------------------------------------------------------------------
__global__ __launch_bounds__(256) void k_aggregate(const unsigned short* __restrict__ feat_bf,
                                                   const float* __restrict__ el,
                                                   const float* __restrict__ er,
                                                   const int* __restrict__ src,
                                                   const int* __restrict__ dst,
                                                   const int* __restrict__ rows,
                                                   float* __restrict__ out) {
    __shared__ float wS[CAP * NH];   // 16 KB
    const int tid = threadIdx.x;
    const int wave = tid >> 6;
    const int lane = tid & 63;
    const int n0 = blockIdx.x * 4;   // NN % 4 == 0: all waves hold a valid node
    const int n  = n0 + wave;

    const int s0 = __builtin_amdgcn_readfirstlane(rows[n0]);
    const int t3 = __builtin_amdgcn_readfirstlane(rows[n0 + 4]);
    const int s  = __builtin_amdgcn_readfirstlane(rows[n]);
    const int t  = __builtin_amdgcn_readfirstlane(rows[n + 1]);

    const int q  = lane >> 4;        // edge slot 0..3
    const int lp = lane & 15;        // dim slot: dims 8*lp .. 8*lp+7
    const int h  = lp >> 2;          // head of those dims
    const int dimoff = 8 * lp;

    float acc[8] = {0.f, 0.f, 0.f, 0.f, 0.f, 0.f, 0.f, 0.f};
    float den = 0.f;

    for (int c0 = s0; c0 < t3; c0 += CAP) {
        const int c1 = min(c0 + CAP, t3);

        // ---- phase 1: per-edge weights into LDS ----
        for (int e = c0 + tid; e < c1; e += 256) {
            int sj = src[e], dj = dst[e];
            float4 l4 = *(const float4*)&el[sj * NH];
            float4 r4 = *(const float4*)&er[dj * NH];
            float4 w; float lg;
            lg = l4.x + r4.x; w.x = __expf(fmaxf(lg, 0.2f * lg));
            lg = l4.y + r4.y; w.y = __expf(fmaxf(lg, 0.2f * lg));
            lg = l4.z + r4.z; w.z = __expf(fmaxf(lg, 0.2f * lg));
            lg = l4.w + r4.w; w.w = __expf(fmaxf(lg, 0.2f * lg));
            *(float4*)&wS[(e - c0) * NH] = w;
        }
        __syncthreads();

        // ---- phase 2: this wave's edges within [c0, c1) ----
        const int sb = max(s, c0), tb = min(t, c1);
        for (int e = (sb & ~3); e < tb; e += 16) {
            const int base = e + 4 * q;      // 4-aligned index -> 16B src addr
            int sj4[4];
            const bool full4 = (base >= sb) && (base + 3 < tb);
            if (full4) {
                int4 sv = *(const int4*)&src[base];
                sj4[0] = sv.x; sj4[1] = sv.y; sj4[2] = sv.z; sj4[3] = sv.w;
            } else {
                #pragma unroll
                for (int u = 0; u < 4; ++u) {
                    int ei = base + u;
                    sj4[u] = (ei >= sb && ei < tb) ? src[ei] : 0;
                }
            }

            float wv4[4];
            uint4 uvv[4];
            #pragma unroll
            for (int u = 0; u < 4; ++u) {
                int ei = base + u;
                bool v = (ei >= sb) && (ei < tb);
                wv4[u] = v ? wS[(ei - c0) * NH + h] : 0.f;
                if (v) uvv[u] = *(const uint4*)&feat_bf[(size_t)sj4[u] * FD + dimoff];
            }

            #pragma unroll
            for (int u = 0; u < 4; ++u) {
                int ei = base + u;
                if (ei >= sb && ei < tb) {
                    float w = wv4[u];
                    uint4 uv = uvv[u];
                    acc[0] += w * bf_lo(uv.x); acc[1] += w * bf_hi(uv.x);
                    acc[2] += w * bf_lo(uv.y); acc[3] += w * bf_hi(uv.y);
                    acc[4] += w * bf_lo(uv.z); acc[5] += w * bf_hi(uv.z);
                    acc[6] += w * bf_lo(uv.w); acc[7] += w * bf_hi(uv.w);
                    den += w;
                }
            }
        }
        __syncthreads();   // before next chunk overwrites wS
    }

    // combine the 4 edge-groups (lanes differing in bits 4,5)
    #pragma unroll
    for (int m = 16; m < 64; m <<= 1) {
        #pragma unroll
        for (int j = 0; j < 8; ++j) acc[j] += __shfl_xor(acc[j], m);
        den += __shfl_xor(den, m);
    }

    if (q == 0) {
        const float rden = (den > 0.f) ? 1.f / den : 0.f;
        float* op = out + (size_t)n * FD + dimoff;
        *(float4*)op       = make_float4(acc[0] * rden, acc[1] * rden, acc[2] * rden, acc[3] * rden);
        *(float4*)(op + 4) = make_float4(acc[4] * rden, acc[5] * rden, acc[6] * rden, acc[7] * rden);
    }
}

// ---------------------------------------------------------------------------
extern "C" void kernel_launch(void* const* d_in, const int* in_sizes, int n_in,
                              void* d_out, int out_size, void* d_ws, size_t ws_size,
                              hipStream_t stream) {
    const float* x  = (const float*)d_in[0];
    const float* W  = (const float*)d_in[1];
    const float* al = (const float*)d_in[2];
    const float* ar = (const float*)d_in[3];
    const int* src  = (const int*)d_in[4];
    const int* dst  = (const int*)d_in[5];
    float* out = (float*)d_out;

    // ws: feat_bf[NN*FD] ushort | el[NN*NH] f32 | er[NN*NH] f32 | rows[NN+1]
    unsigned short* feat_bf = (unsigned short*)d_ws;
    float* el = (float*)(feat_bf + (size_t)NN * FD);
    float* er = el + (size_t)NN * NH;
    int*   rows = (int*)(er + (size_t)NN * NH);

    k_gemm_rows<<<GEMM_BLOCKS + ROWS_BLOCKS, 512, 0, stream>>>(x, W, al, ar, dst,
                                                               feat_bf, el, er, rows);
    k_aggregate<<<NN / 4, 256, 0, stream>>>(feat_bf, el, er, src, dst, rows, out);
}

// Round 3
// 130.823 us; speedup vs baseline: 1.0871x; 1.0418x over previous
//
#include <hip/hip_runtime.h>
#include <math.h>

#define NN 50000
#define NE 800000
#define NH 4
#define HD 32
#define FD 128      // NH*HD == IN_DIM
#define NTILE 3125  // 50000 / 16 exactly
#define GEMM_BLOCKS 512                 // grid-stride, 8 waves/block, 2 blocks/CU
#define ROWS_BLOCKS ((NE + 511) / 512)  // 1563
#define CAP 1024    // edges per LDS chunk; typical block degree ~64

typedef __attribute__((ext_vector_type(8))) short short8;
typedef __attribute__((ext_vector_type(4))) float floatx4;

__device__ __forceinline__ unsigned short f2bf(float f) {
    union { float f; unsigned u; } v; v.f = f;
    unsigned u = v.u;
    return (unsigned short)((u + 0x7FFFu + ((u >> 16) & 1u)) >> 16);
}
__device__ __forceinline__ float bfu(unsigned short u) {
    union { unsigned u; float f; } v; v.u = (unsigned)u << 16; return v.f;
}
__device__ __forceinline__ float bf_lo(unsigned u) {
    union { unsigned u; float f; } v; v.u = u << 16; return v.f;
}
__device__ __forceinline__ float bf_hi(unsigned u) {
    union { unsigned u; float f; } v; v.u = u & 0xFFFF0000u; return v.f;
}

// ---------------------------------------------------------------------------
// Kernel 1: projection via bf16 MFMA. el/er are computed by 4 EXTRA MFMAs
// against a per-block precomputed Wa = W^T [a_l | a_r] tile (8 cols), NOT by
// a cross-lane shuffle reduce — el = feat.a_l = x.(W^T a_l). This removes the
// serial 16-shuffle chain per tile that dominated the epilogue.
// CSR row-offset builder fused as trailing blocks (overlaps the GEMM).
// ---------------------------------------------------------------------------
__global__ __launch_bounds__(512) void k_gemm_rows(const float* __restrict__ x,
                                                   const float* __restrict__ W,
                                                   const float* __restrict__ al,
                                                   const float* __restrict__ ar,
                                                   const int* __restrict__ dst,
                                                   unsigned short* __restrict__ feat_bf,
                                                   float* __restrict__ el,
                                                   float* __restrict__ er,
                                                   int* __restrict__ rows) {
    const int tid = threadIdx.x;

    if (blockIdx.x >= GEMM_BLOCKS) {
        // ---- CSR row offsets from sorted dst ----
        int e = (blockIdx.x - GEMM_BLOCKS) * 512 + tid;
        if (e < NE) {
            int dj = dst[e];
            if (e == 0) {
                for (int n = 0; n <= dj; ++n) rows[n] = 0;
            } else {
                int prev = dst[e - 1];
                for (int n = prev + 1; n <= dj; ++n) rows[n] = e;
            }
            if (e == NE - 1) {
                for (int n = dj + 1; n <= NN; ++n) rows[n] = NE;
            }
        }
        return;
    }

    __shared__ unsigned short Wl[FD * 136];    // Wl[c][k], row stride 136 bf16
    __shared__ unsigned short WaL[16 * 136];   // Wa[c][k]: c<8 = W^T[a_l|a_r], c>=8 zero
    __shared__ float aS[2 * FD];               // al | ar

    for (int p = tid; p < FD * 64; p += 512) {
        int c = p >> 6, k2 = (p & 63) * 2;
        float2 wv = *(const float2*)&W[c * FD + k2];
        *(unsigned*)&Wl[c * 136 + k2] =
            (unsigned)f2bf(wv.x) | ((unsigned)f2bf(wv.y) << 16);
    }
    if (tid < FD) aS[tid] = al[tid];
    else if (tid < 2 * FD) aS[tid] = ar[tid - FD];
    __syncthreads();

    // Wa[c][k] = sum_d a[c][d] * W[32h+d][k], h = c&3; one-time per block.
    for (int p = tid; p < 16 * FD; p += 512) {
        int c = p >> 7, k = p & 127;
        float v = 0.f;
        if (c < 8) {
            int h = c & 3;
            const float* av = &aS[(c >> 2) * FD + h * HD];
            const unsigned short* wl = &Wl[h * HD * 136 + k];
            #pragma unroll 8
            for (int d = 0; d < HD; ++d) v += bfu(wl[d * 136]) * av[d];
        }
        WaL[c * 136 + k] = f2bf(v);
    }
    __syncthreads();

    const int wv_id = tid >> 6, lane = tid & 63;
    const int col = lane & 15, quad = lane >> 4;

    for (int tile = blockIdx.x * 8 + wv_id; tile < NTILE; tile += GEMM_BLOCKS * 8) {
        const int n0 = tile * 16;

        short8 afrag[4];
        const float* xrow = x + (size_t)(n0 + col) * FD;
        #pragma unroll
        for (int s = 0; s < 4; ++s) {
            float4 u0 = *(const float4*)&xrow[s * 32 + quad * 8];
            float4 u1 = *(const float4*)&xrow[s * 32 + quad * 8 + 4];
            short8 a;
            a[0] = (short)f2bf(u0.x); a[1] = (short)f2bf(u0.y);
            a[2] = (short)f2bf(u0.z); a[3] = (short)f2bf(u0.w);
            a[4] = (short)f2bf(u1.x); a[5] = (short)f2bf(u1.y);
            a[6] = (short)f2bf(u1.z); a[7] = (short)f2bf(u1.w);
            afrag[s] = a;
        }

        floatx4 acc[8], acce;
        #pragma unroll
        for (int ct = 0; ct < 8; ++ct) acc[ct] = (floatx4){0.f, 0.f, 0.f, 0.f};
        acce = (floatx4){0.f, 0.f, 0.f, 0.f};

        #pragma unroll
        for (int ct = 0; ct < 8; ++ct) {
            #pragma unroll
            for (int s = 0; s < 4; ++s) {
                short8 b = *(const short8*)&Wl[(ct * 16 + col) * 136 + s * 32 + quad * 8];
                acc[ct] = __builtin_amdgcn_mfma_f32_16x16x32_bf16(afrag[s], b, acc[ct], 0, 0, 0);
            }
        }
        #pragma unroll
        for (int s = 0; s < 4; ++s) {
            short8 b = *(const short8*)&WaL[col * 136 + s * 32 + quad * 8];
            acce = __builtin_amdgcn_mfma_f32_16x16x32_bf16(afrag[s], b, acce, 0, 0, 0);
        }

        // feat store (C/D: col = lane&15, row = quad*4 + reg)
        #pragma unroll
        for (int ct = 0; ct < 8; ++ct) {
            #pragma unroll
            for (int r = 0; r < 4; ++r) {
                feat_bf[(size_t)(n0 + quad * 4 + r) * FD + ct * 16 + col] = f2bf(acc[ct][r]);
            }
        }
        // el/er store: acce col 0..3 = el heads, col 4..7 = er heads
        #pragma unroll
        for (int r = 0; r < 4; ++r) {
            int n = n0 + quad * 4 + r;
            if (col < 4)      el[n * NH + col]     = acce[r];
            else if (col < 8) er[n * NH + col - 4] = acce[r];
        }
    }
}

// ---------------------------------------------------------------------------
// Kernel 2: aggregation with BLOCK-LOCAL LDS weights AND LDS src indices.
// Block = 4 consecutive nodes = one contiguous CSR edge range.
// Phase 1: 256 threads compute w[e][h] once per edge into LDS and stage
//   src[e] into LDS (already loaded anyway).
// Phase 2: per-wave gather loop (lane = 16*edge_slot + dim_slot); src and w
//   come from LDS (short dependent chain: ds_read -> feat gather), tails
//   exec-masked, no alignment handling needed.
// ---------------------------------------------------------------------------
__global__ __launch_bounds__(256) void k_aggregate(const unsigned short* __restrict__ feat_bf,
                                                   const float* __restrict__ el,
                                                   const float* __restrict__ er,
                                                   const int* __restrict__ src,
                                                   const int* __restrict__ dst,
                                                   const int* __restrict__ rows,
                                                   float* __restrict__ out) {
    __shared__ float wS[CAP * NH];   // 16 KB
    __shared__ int   sS[CAP];        // 4 KB
    const int tid = threadIdx.x;
    const int wave = tid >> 6;
    const int lane = tid & 63;
    const int n0 = blockIdx.x * 4;   // NN % 4 == 0
    const int n  = n0 + wave;

    const int s0 = __builtin_amdgcn_readfirstlane(rows[n0]);
    const int t3 = __builtin_amdgcn_readfirstlane(rows[n0 + 4]);
    const int s  = __builtin_amdgcn_readfirstlane(rows[n]);
    const int t  = __builtin_amdgcn_readfirstlane(rows[n + 1]);

    const int q  = lane >> 4;        // edge slot 0..3
    const int lp = lane & 15;        // dim slot: dims 8*lp .. 8*lp+7
    const int h  = lp >> 2;          // head of those dims
    const int dimoff = 8 * lp;

    float acc[8] = {0.f, 0.f, 0.f, 0.f, 0.f, 0.f, 0.f, 0.f};
    float den = 0.f;

    for (int c0 = s0; c0 < t3; c0 += CAP) {
        const int c1 = min(c0 + CAP, t3);

        // ---- phase 1: per-edge weights + src into LDS ----
        for (int e = c0 + tid; e < c1; e += 256) {
            int sj = src[e], dj = dst[e];
            sS[e - c0] = sj;
            float4 l4 = *(const float4*)&el[sj * NH];
            float4 r4 = *(const float4*)&er[dj * NH];
            float4 w; float lg;
            lg = l4.x + r4.x; w.x = __expf(fmaxf(lg, 0.2f * lg));
            lg = l4.y + r4.y; w.y = __expf(fmaxf(lg, 0.2f * lg));
            lg = l4.z + r4.z; w.z = __expf(fmaxf(lg, 0.2f * lg));
            lg = l4.w + r4.w; w.w = __expf(fmaxf(lg, 0.2f * lg));
            *(float4*)&wS[(e - c0) * NH] = w;
        }
        __syncthreads();

        // ---- phase 2: this wave's edges within [c0, c1) ----
        const int sb = max(s, c0), tb = min(t, c1);
        for (int e = sb; e < tb; e += 16) {
            const int base = e + 4 * q;
            float wv4[4];
            int   sj4[4];
            uint4 uvv[4];
            #pragma unroll
            for (int u = 0; u < 4; ++u) {
                int ei = base + u;
                bool v = ei < tb;                      // ei >= sb guaranteed
                int ii = v ? (ei - c0) : 0;            // clamped: LDS-safe
                sj4[u] = sS[ii];
                wv4[u] = v ? wS[ii * NH + h] : 0.f;
                if (v) uvv[u] = *(const uint4*)&feat_bf[(size_t)sj4[u] * FD + dimoff];
            }
            #pragma unroll
            for (int u = 0; u < 4; ++u) {
                int ei = base + u;
                if (ei < tb) {
                    float w = wv4[u];
                    uint4 uv = uvv[u];
                    acc[0] += w * bf_lo(uv.x); acc[1] += w * bf_hi(uv.x);
                    acc[2] += w * bf_lo(uv.y); acc[3] += w * bf_hi(uv.y);
                    acc[4] += w * bf_lo(uv.z); acc[5] += w * bf_hi(uv.z);
                    acc[6] += w * bf_lo(uv.w); acc[7] += w * bf_hi(uv.w);
                    den += w;
                }
            }
        }
        __syncthreads();   // before next chunk overwrites wS/sS
    }

    // combine the 4 edge-groups (lanes differing in bits 4,5)
    #pragma unroll
    for (int m = 16; m < 64; m <<= 1) {
        #pragma unroll
        for (int j = 0; j < 8; ++j) acc[j] += __shfl_xor(acc[j], m);
        den += __shfl_xor(den, m);
    }

    if (q == 0) {
        const float rden = (den > 0.f) ? 1.f / den : 0.f;
        float* op = out + (size_t)n * FD + dimoff;
        *(float4*)op       = make_float4(acc[0] * rden, acc[1] * rden, acc[2] * rden, acc[3] * rden);
        *(float4*)(op + 4) = make_float4(acc[4] * rden, acc[5] * rden, acc[6] * rden, acc[7] * rden);
    }
}

// ---------------------------------------------------------------------------
extern "C" void kernel_launch(void* const* d_in, const int* in_sizes, int n_in,
                              void* d_out, int out_size, void* d_ws, size_t ws_size,
                              hipStream_t stream) {
    const float* x  = (const float*)d_in[0];
    const float* W  = (const float*)d_in[1];
    const float* al = (const float*)d_in[2];
    const float* ar = (const float*)d_in[3];
    const int* src  = (const int*)d_in[4];
    const int* dst  = (const int*)d_in[5];
    float* out = (float*)d_out;

    // ws: feat_bf[NN*FD] ushort | el[NN*NH] f32 | er[NN*NH] f32 | rows[NN+1]
    unsigned short* feat_bf = (unsigned short*)d_ws;
    float* el = (float*)(feat_bf + (size_t)NN * FD);
    float* er = el + (size_t)NN * NH;
    int*   rows = (int*)(er + (size_t)NN * NH);

    k_gemm_rows<<<GEMM_BLOCKS + ROWS_BLOCKS, 512, 0, stream>>>(x, W, al, ar, dst,
                                                               feat_bf, el, er, rows);
    k_aggregate<<<NN / 4, 256, 0, stream>>>(feat_bf, el, er, src, dst, rows, out);
}